// Round 10
// baseline (203.049 us; speedup 1.0000x reference)
//
#include <hip/hip_runtime.h>
#include <math.h>

// N=2048, DH=256, DK=64, FF=32. fp32 in/out, f16 internal.
// ws layout (bytes):
//   q16   @ 0       : 2048x64   f16  (262144)
//   k16   @ 262144  : 2048x64   f16  (262144)
//   vT    @ 524288  : 256x2048  f16  (v transposed)  (1048576)
//   focus @ 1572864 : 2048x2048 f16  (8388608)
// total ~9.96 MB. Scores are never materialized (fused into k_mlp).

#define NN  2048
#define DHH 256
#define DKK 64

typedef float    f32x4 __attribute__((ext_vector_type(4)));
typedef _Float16 f16x8 __attribute__((ext_vector_type(8)));
typedef _Float16 f16x4 __attribute__((ext_vector_type(4)));
typedef _Float16 f16x2 __attribute__((ext_vector_type(2)));
typedef int      i32x2 __attribute__((ext_vector_type(2)));

// gfx908-lineage builtin, still present on gfx950 (ISA §10: v_mfma_f32_16x16x16_f16).
// NOTE: no __has_builtin guard — it returns false on the HOST pass (x86 target)
// even though the builtin is declared for both passes, which broke R9.
#define MFMA16(a, b, c) __builtin_amdgcn_mfma_f32_16x16x16f16((a), (b), (c), 0, 0, 0)
#define MFMA32(a, b, c) __builtin_amdgcn_mfma_f32_16x16x32_f16((a), (b), (c), 0, 0, 0)

// ---------------------------------------------------------------------------
// K1: qkv projections (fp32 math). q,k stored f16 row-major; v stored f16
// transposed. grid (32, 6): y=0 q, y=1 k, y=2..5 v col-groups.
// ---------------------------------------------------------------------------
__global__ __launch_bounds__(256) void k_qkv(
    const float* __restrict__ x,
    const float* __restrict__ Wq, const float* __restrict__ bq,
    const float* __restrict__ Wk, const float* __restrict__ bk,
    const float* __restrict__ Wv, const float* __restrict__ bv,
    _Float16* __restrict__ q16, _Float16* __restrict__ k16,
    _Float16* __restrict__ vT)
{
    __shared__ float As[32][64];
    __shared__ float Bs[32][64];
    __shared__ _Float16 Ts[64 * 72];

    const int t  = threadIdx.x;
    const int m0 = blockIdx.x * 64;
    const int yb = blockIdx.y;

    const float* W; const float* bias; int wld; int cw0;
    if (yb == 0)      { W = Wq; bias = bq; wld = 64;  cw0 = 0; }
    else if (yb == 1) { W = Wk; bias = bk; wld = 64;  cw0 = 0; }
    else              { W = Wv; bias = bv; wld = 256; cw0 = (yb - 2) * 64; }

    const int tx = t & 15, ty = t >> 4;
    float acc[4][4] = {};

    for (int k0 = 0; k0 < DHH; k0 += 32) {
        {
            const int rr = t >> 3;
            const int cc = (t & 7) * 4;
            float4 a0 = *(const float4*)(x + (size_t)(m0 + rr)      * DHH + k0 + cc);
            float4 a1 = *(const float4*)(x + (size_t)(m0 + rr + 32) * DHH + k0 + cc);
            As[cc+0][rr]    = a0.x; As[cc+1][rr]    = a0.y; As[cc+2][rr]    = a0.z; As[cc+3][rr]    = a0.w;
            As[cc+0][rr+32] = a1.x; As[cc+1][rr+32] = a1.y; As[cc+2][rr+32] = a1.z; As[cc+3][rr+32] = a1.w;
        }
        {
            const int bk_ = t >> 4;
            const int bc  = (t & 15) * 4;
            *(float4*)&Bs[bk_][bc]      = *(const float4*)(W + (size_t)(k0 + bk_)      * wld + cw0 + bc);
            *(float4*)&Bs[bk_ + 16][bc] = *(const float4*)(W + (size_t)(k0 + bk_ + 16) * wld + cw0 + bc);
        }
        __syncthreads();
        #pragma unroll
        for (int kk = 0; kk < 32; ++kk) {
            float4 a = *(const float4*)&As[kk][ty * 4];
            float4 b = *(const float4*)&Bs[kk][tx * 4];
            float av[4] = {a.x, a.y, a.z, a.w};
            float bw[4] = {b.x, b.y, b.z, b.w};
            #pragma unroll
            for (int ii = 0; ii < 4; ++ii)
                #pragma unroll
                for (int jj = 0; jj < 4; ++jj)
                    acc[ii][jj] = fmaf(av[ii], bw[jj], acc[ii][jj]);
        }
        __syncthreads();
    }

    float4 b4 = *(const float4*)&bias[cw0 + tx * 4];
    float bc4[4] = {b4.x, b4.y, b4.z, b4.w};

    if (yb < 2) {
        _Float16* outp = (yb == 0) ? q16 : k16;
        #pragma unroll
        for (int ii = 0; ii < 4; ++ii) {
            f16x4 hv;
            #pragma unroll
            for (int jj = 0; jj < 4; ++jj) hv[jj] = (_Float16)(acc[ii][jj] + bc4[jj]);
            *(f16x4*)&outp[(size_t)(m0 + ty * 4 + ii) * 64 + tx * 4] = hv;
        }
    } else {
        #pragma unroll
        for (int jj = 0; jj < 4; ++jj) {
            f16x4 hv;
            #pragma unroll
            for (int ii = 0; ii < 4; ++ii) hv[ii] = (_Float16)(acc[ii][jj] + bc4[jj]);
            *(f16x4*)&Ts[(tx * 4 + jj) * 72 + ty * 4] = hv;
        }
        __syncthreads();
        {
            const int c = t >> 2, seg = t & 3;
            f16x8 r0 = *(const f16x8*)&Ts[c * 72 + seg * 16];
            f16x8 r1 = *(const f16x8*)&Ts[c * 72 + seg * 16 + 8];
            *(f16x8*)&vT[(size_t)(cw0 + c) * NN + m0 + seg * 16]     = r0;
            *(f16x8*)&vT[(size_t)(cw0 + c) * NN + m0 + seg * 16 + 8] = r1;
        }
    }
}

// ---------------------------------------------------------------------------
// K2 (fused scores+MLP+softmax): one block per row i, 4 independent waves.
// Per 16-edge step st:
//   s-MFMA (16x16x32): A = k_i broadcast (loop-invariant), B = Q rows ->
//     C[m][e] identical over m; s = exact f32 dot. No score materialization.
//   layer 1 (2x 16x16x16): B1 k-slots {s_hi, s_lo, a, d | s_hi} built
//     per-lane (only 1 bpermute: a/d gather); A = W1 frags (static);
//     bias via C-init.
//   layer 2 (4x 16x16x16, K-split chained): B2 k=4q+j matches layer-1 C
//     rows q*4+r exactly -> per-lane relu+pack, ZERO cross-lane.
//   layer 3: 8 relu-fma + xor16/32 reduce (2 LDS-pipe ops).
// Logits in registers; block softmax; focus (f16, compact) out.
// ---------------------------------------------------------------------------
__global__ __launch_bounds__(256) void k_mlp(
    const _Float16* __restrict__ q16, const _Float16* __restrict__ k16,
    const float* __restrict__ adj, const float* __restrict__ dense,
    const float* __restrict__ W1, const float* __restrict__ b1,
    const float* __restrict__ W2, const float* __restrict__ b2,
    const float* __restrict__ W3,
    _Float16* __restrict__ focus)
{
    __shared__ float red[8];

    const int t    = threadIdx.x;
    const int lane = t & 63;
    const int w    = t >> 6;
    const int col  = lane & 15;
    const int q    = lane >> 4;
    const int i    = blockIdx.x;

    // ---- s-MFMA A: k_i broadcast (every lane holds k_i[8q+j] / [32+8q+j]) ----
    const f16x8 kA0 = *(const f16x8*)&k16[(size_t)i * 64 + q * 8];
    const f16x8 kA1 = *(const f16x8*)&k16[(size_t)i * 64 + 32 + q * 8];

    // ---- layer-1 A frags (16x16x16; k=4q+j). Slots: k0=W0hi, k1=W0hi,
    //      k2=W1_1, k3=W1_2, k4=W0lo, rest 0. l1A0 -> feats 0..15 (m=col),
    //      l1A1 -> feats 16..31.
    f16x4 l1A0 = {}, l1A1 = {};
    {
        const float w0a = W1[col], w0b = W1[col + 16];
        const _Float16 h0a = (_Float16)w0a, h0b = (_Float16)w0b;
        if (q == 0) {
            l1A0[0] = h0a; l1A0[1] = h0a;
            l1A0[2] = (_Float16)W1[32 + col];
            l1A0[3] = (_Float16)W1[64 + col];
            l1A1[0] = h0b; l1A1[1] = h0b;
            l1A1[2] = (_Float16)W1[32 + col + 16];
            l1A1[3] = (_Float16)W1[64 + col + 16];
        } else if (q == 1) {
            l1A0[0] = (_Float16)(w0a - (float)h0a);
            l1A1[0] = (_Float16)(w0b - (float)h0b);
        }
    }

    // ---- layer-2 A frags: w2A[fh][oh][j] = W2[fh*16 + 4q+j][oh*16 + col] ----
    f16x4 w2A[2][2];
    #pragma unroll
    for (int fh = 0; fh < 2; ++fh)
        #pragma unroll
        for (int oh = 0; oh < 2; ++oh)
            #pragma unroll
            for (int j = 0; j < 4; ++j)
                w2A[fh][oh][j] = (_Float16)W2[(fh * 16 + q * 4 + j) * 32 + oh * 16 + col];

    // ---- biases / W3 (indexed by feat/out = q*4+r) ----
    f32x4 c1a, c1b, c2a, c2b, w3v, w3v2;
    #pragma unroll
    for (int r = 0; r < 4; ++r) {
        c1a[r]  = b1[q * 4 + r];
        c1b[r]  = b1[16 + q * 4 + r];
        c2a[r]  = b2[q * 4 + r];
        c2b[r]  = b2[16 + q * 4 + r];
        w3v[r]  = W3[q * 4 + r];
        w3v2[r] = W3[16 + q * 4 + r];
    }

    const float* arow = adj   + (size_t)i * NN;
    const float* drow = dense + (size_t)i * NN;

    const f32x4 zero4 = {0.f, 0.f, 0.f, 0.f};
    float lg[8];

    for (int c = 0; c < 8; ++c) {
        const int base = w * 512 + c * 64;
        const int jj   = base + lane;

        // per-lane (a, d) for edge jj, gathered per st below
        const int u_ad = __builtin_bit_cast(int,
            __builtin_amdgcn_cvt_pkrtz(arow[jj], drow[jj]));

        float lgc = 0.f;
        #pragma unroll
        for (int st = 0; st < 4; ++st) {
            const int edge = base + st * 16 + col;

            // ---- fused score: s = <k_i, q_edge> (exact f32) ----
            f16x8 Qb0 = *(const f16x8*)&q16[(size_t)edge * 64 + q * 8];
            f16x8 Qb1 = *(const f16x8*)&q16[(size_t)edge * 64 + 32 + q * 8];
            f32x4 sC = MFMA32(kA0, Qb0, zero4);
            sC = MFMA32(kA1, Qb1, sC);
            const float s = sC[0];          // rows identical (A broadcast)

            // ---- build B1 (f16x4 = k slots 4q..4q+3) ----
            const _Float16 shi = (_Float16)s;
            _Float16 slo = (_Float16)(s - (float)shi);
            if (q == 1) slo = (_Float16)0;  // q1 slot k5 must be 0
            f16x2 r0; r0[0] = shi; r0[1] = slo;
            const int ad = __shfl(u_ad, st * 16 + col, 64);
            i32x2 b1v = { __builtin_bit_cast(int, r0), ad };
            f16x4 B1 = __builtin_bit_cast(f16x4, b1v);

            // ---- layer 1 ----
            f32x4 hpA = MFMA16(l1A0, B1, c1a);
            f32x4 hpB = MFMA16(l1A1, B1, c1b);

            // ---- relu + pack: C rows q*4+r == B2 k-slots 4q+j (no shfl!) ----
            i32x2 p0 = { __builtin_bit_cast(int, __builtin_amdgcn_cvt_pkrtz(fmaxf(hpA[0], 0.f), fmaxf(hpA[1], 0.f))),
                         __builtin_bit_cast(int, __builtin_amdgcn_cvt_pkrtz(fmaxf(hpA[2], 0.f), fmaxf(hpA[3], 0.f))) };
            i32x2 p1 = { __builtin_bit_cast(int, __builtin_amdgcn_cvt_pkrtz(fmaxf(hpB[0], 0.f), fmaxf(hpB[1], 0.f))),
                         __builtin_bit_cast(int, __builtin_amdgcn_cvt_pkrtz(fmaxf(hpB[2], 0.f), fmaxf(hpB[3], 0.f))) };
            f16x4 B2f0 = __builtin_bit_cast(f16x4, p0);   // feats 0..15
            f16x4 B2f1 = __builtin_bit_cast(f16x4, p1);   // feats 16..31

            // ---- layer 2 (K-split chained) ----
            f32x4 acc0 = MFMA16(w2A[0][0], B2f0, c2a);
            acc0 = MFMA16(w2A[1][0], B2f1, acc0);
            f32x4 acc1 = MFMA16(w2A[0][1], B2f0, c2b);
            acc1 = MFMA16(w2A[1][1], B2f1, acc1);

            // ---- layer 3 ----
            float p = 0.f;
            #pragma unroll
            for (int r = 0; r < 4; ++r) {
                p = fmaf(fmaxf(acc0[r], 0.f), w3v[r],  p);
                p = fmaf(fmaxf(acc1[r], 0.f), w3v2[r], p);
            }
            p += __shfl_xor(p, 16, 64);
            p += __shfl_xor(p, 32, 64);
            lgc = (q == st) ? p : lgc;      // lane (q,col) keeps edge q*16+col
        }
        lg[c] = lgc;
    }

    // ---- row softmax (logits in registers; edge = w*512+c*64+q*16+col) ----
    float lmax = -1e30f;
    #pragma unroll
    for (int u = 0; u < 8; ++u) lmax = fmaxf(lmax, lg[u]);
    #pragma unroll
    for (int off = 32; off > 0; off >>= 1)
        lmax = fmaxf(lmax, __shfl_xor(lmax, off, 64));
    if (lane == 0) red[w] = lmax;
    __syncthreads();
    const float rmax = fmaxf(fmaxf(red[0], red[1]), fmaxf(red[2], red[3]));

    float lsum = 0.f;
    #pragma unroll
    for (int u = 0; u < 8; ++u) { lg[u] = __expf(lg[u] - rmax); lsum += lg[u]; }
    #pragma unroll
    for (int off = 32; off > 0; off >>= 1)
        lsum += __shfl_xor(lsum, off, 64);
    if (lane == 0) red[4 + w] = lsum;
    __syncthreads();
    const float inv = 1.f / (red[4] + red[5] + red[6] + red[7]);

    _Float16* hrow = focus + (size_t)i * NN;
    const int eb = w * 512 + q * 16 + col;
    #pragma unroll
    for (int u = 0; u < 8; ++u)
        hrow[eb + u * 64] = (_Float16)(lg[u] * inv);
}

// ---------------------------------------------------------------------------
// K3: feature = focus @ v via f16 MFMA, K split 4-way across waves + LDS
// reduce. grid (8,128). focus compact (row stride NN).
// ---------------------------------------------------------------------------
__global__ __launch_bounds__(256) void k_feat(
    const _Float16* __restrict__ focus, const _Float16* __restrict__ vT,
    float* __restrict__ out)
{
    __shared__ float rbuf[3][64][8];

    const int t    = threadIdx.x;
    const int lane = t & 63;
    const int w    = t >> 6;
    const int col  = lane & 15;
    const int q    = lane >> 4;

    const int m0 = blockIdx.y * 16;
    const int n0 = blockIdx.x * 32;

    f32x4 acc0 = {}, acc1 = {};

    const size_t arow  = (size_t)(m0 + col) * NN;
    const size_t brow0 = (size_t)(n0 + col) * NN;
    const size_t brow1 = (size_t)(n0 + 16 + col) * NN;
    const int kb = w * 512 + q * 8;

    #pragma unroll 4
    for (int k0 = 0; k0 < 512; k0 += 32) {
        const int ko = kb + k0;
        f16x8 a  = *(const f16x8*)&focus[arow + ko];
        f16x8 b0 = *(const f16x8*)&vT[brow0 + ko];
        f16x8 b1 = *(const f16x8*)&vT[brow1 + ko];
        acc0 = MFMA32(a, b0, acc0);
        acc1 = MFMA32(a, b1, acc1);
    }

    if (w != 0) {
        *(float4*)&rbuf[w - 1][lane][0] = *(float4*)&acc0;
        *(float4*)&rbuf[w - 1][lane][4] = *(float4*)&acc1;
    }
    __syncthreads();

    if (w == 0) {
        #pragma unroll
        for (int j = 0; j < 3; ++j) {
            float4 p0 = *(const float4*)&rbuf[j][lane][0];
            float4 p1 = *(const float4*)&rbuf[j][lane][4];
            acc0[0] += p0.x; acc0[1] += p0.y; acc0[2] += p0.z; acc0[3] += p0.w;
            acc1[0] += p1.x; acc1[1] += p1.y; acc1[2] += p1.z; acc1[3] += p1.w;
        }
        #pragma unroll
        for (int r = 0; r < 4; ++r) {
            out[(size_t)(m0 + q * 4 + r) * DHH + n0 + col]      = acc0[r];
            out[(size_t)(m0 + q * 4 + r) * DHH + n0 + 16 + col] = acc1[r];
        }
    }
}

// ---------------------------------------------------------------------------
extern "C" void kernel_launch(void* const* d_in, const int* in_sizes, int n_in,
                              void* d_out, int out_size, void* d_ws, size_t ws_size,
                              hipStream_t stream) {
    const float* x     = (const float*)d_in[0];
    const float* adj   = (const float*)d_in[1];
    const float* dense = (const float*)d_in[2];
    const float* Wq    = (const float*)d_in[3];
    const float* bq    = (const float*)d_in[4];
    const float* Wk    = (const float*)d_in[5];
    const float* bk    = (const float*)d_in[6];
    const float* Wv    = (const float*)d_in[7];
    const float* bv    = (const float*)d_in[8];
    const float* W1    = (const float*)d_in[9];
    const float* b1    = (const float*)d_in[10];
    const float* W2    = (const float*)d_in[11];
    const float* b2    = (const float*)d_in[12];
    const float* W3    = (const float*)d_in[13];
    float* out = (float*)d_out;

    char* wsb = (char*)d_ws;
    _Float16* q16   = (_Float16*)(wsb);
    _Float16* k16   = (_Float16*)(wsb + 262144);
    _Float16* vT    = (_Float16*)(wsb + 524288);
    _Float16* focus = (_Float16*)(wsb + 1572864);

    hipLaunchKernelGGL(k_qkv,  dim3(32, 6),  dim3(256), 0, stream,
                       x, Wq, bq, Wk, bk, Wv, bv, q16, k16, vT);
    hipLaunchKernelGGL(k_mlp,  dim3(2048),   dim3(256), 0, stream,
                       q16, k16, adj, dense, W1, b1, W2, b2, W3, focus);
    hipLaunchKernelGGL(k_feat, dim3(8, 128), dim3(256), 0, stream,
                       focus, vT, out);
}

// Round 11
// 189.512 us; speedup vs baseline: 1.0714x; 1.0714x over previous
//
#include <hip/hip_runtime.h>
#include <math.h>

// N=2048, DH=256, DK=64, FF=32. fp32 in/out, f16 internal.
// ws layout (bytes):
//   q16  @ 0        : 2048x64   f16    (262144)
//   k16  @ 262144   : 2048x64   f16    (262144)
//   vT   @ 524288   : 256x2048  f16    (v transposed)  (1048576)
//   schl @ 1572864  : 2048x2048 f16x2  packed (score_hi, score_lo) (16777216)
//     -> focus (f16) overwrites first half of each schl row in-place;
//        k_feat reads it with row stride 2*NN halves.
// total 18350080 B (~17.5 MB, proven size)

#define NN  2048
#define DHH 256
#define DKK 64

typedef float    f32x4 __attribute__((ext_vector_type(4)));
typedef _Float16 f16x8 __attribute__((ext_vector_type(8)));
typedef _Float16 f16x4 __attribute__((ext_vector_type(4)));
typedef _Float16 f16x2 __attribute__((ext_vector_type(2)));
typedef int      i32x2 __attribute__((ext_vector_type(2)));

// no __has_builtin guard — returns false on the HOST pass (broke R9)
#define MFMA16(a, b, c) __builtin_amdgcn_mfma_f32_16x16x16f16((a), (b), (c), 0, 0, 0)
#define MFMA32(a, b, c) __builtin_amdgcn_mfma_f32_16x16x32_f16((a), (b), (c), 0, 0, 0)

// ---------------------------------------------------------------------------
// K1: qkv projections (fp32 math). q,k stored f16 row-major; v stored f16
// transposed. grid (32, 6).
// ---------------------------------------------------------------------------
__global__ __launch_bounds__(256) void k_qkv(
    const float* __restrict__ x,
    const float* __restrict__ Wq, const float* __restrict__ bq,
    const float* __restrict__ Wk, const float* __restrict__ bk,
    const float* __restrict__ Wv, const float* __restrict__ bv,
    _Float16* __restrict__ q16, _Float16* __restrict__ k16,
    _Float16* __restrict__ vT)
{
    __shared__ float As[32][64];
    __shared__ float Bs[32][64];
    __shared__ _Float16 Ts[64 * 72];

    const int t  = threadIdx.x;
    const int m0 = blockIdx.x * 64;
    const int yb = blockIdx.y;

    const float* W; const float* bias; int wld; int cw0;
    if (yb == 0)      { W = Wq; bias = bq; wld = 64;  cw0 = 0; }
    else if (yb == 1) { W = Wk; bias = bk; wld = 64;  cw0 = 0; }
    else              { W = Wv; bias = bv; wld = 256; cw0 = (yb - 2) * 64; }

    const int tx = t & 15, ty = t >> 4;
    float acc[4][4] = {};

    for (int k0 = 0; k0 < DHH; k0 += 32) {
        {
            const int rr = t >> 3;
            const int cc = (t & 7) * 4;
            float4 a0 = *(const float4*)(x + (size_t)(m0 + rr)      * DHH + k0 + cc);
            float4 a1 = *(const float4*)(x + (size_t)(m0 + rr + 32) * DHH + k0 + cc);
            As[cc+0][rr]    = a0.x; As[cc+1][rr]    = a0.y; As[cc+2][rr]    = a0.z; As[cc+3][rr]    = a0.w;
            As[cc+0][rr+32] = a1.x; As[cc+1][rr+32] = a1.y; As[cc+2][rr+32] = a1.z; As[cc+3][rr+32] = a1.w;
        }
        {
            const int bk_ = t >> 4;
            const int bc  = (t & 15) * 4;
            *(float4*)&Bs[bk_][bc]      = *(const float4*)(W + (size_t)(k0 + bk_)      * wld + cw0 + bc);
            *(float4*)&Bs[bk_ + 16][bc] = *(const float4*)(W + (size_t)(k0 + bk_ + 16) * wld + cw0 + bc);
        }
        __syncthreads();
        #pragma unroll
        for (int kk = 0; kk < 32; ++kk) {
            float4 a = *(const float4*)&As[kk][ty * 4];
            float4 b = *(const float4*)&Bs[kk][tx * 4];
            float av[4] = {a.x, a.y, a.z, a.w};
            float bw[4] = {b.x, b.y, b.z, b.w};
            #pragma unroll
            for (int ii = 0; ii < 4; ++ii)
                #pragma unroll
                for (int jj = 0; jj < 4; ++jj)
                    acc[ii][jj] = fmaf(av[ii], bw[jj], acc[ii][jj]);
        }
        __syncthreads();
    }

    float4 b4 = *(const float4*)&bias[cw0 + tx * 4];
    float bc4[4] = {b4.x, b4.y, b4.z, b4.w};

    if (yb < 2) {
        _Float16* outp = (yb == 0) ? q16 : k16;
        #pragma unroll
        for (int ii = 0; ii < 4; ++ii) {
            f16x4 hv;
            #pragma unroll
            for (int jj = 0; jj < 4; ++jj) hv[jj] = (_Float16)(acc[ii][jj] + bc4[jj]);
            *(f16x4*)&outp[(size_t)(m0 + ty * 4 + ii) * 64 + tx * 4] = hv;
        }
    } else {
        #pragma unroll
        for (int jj = 0; jj < 4; ++jj) {
            f16x4 hv;
            #pragma unroll
            for (int ii = 0; ii < 4; ++ii) hv[ii] = (_Float16)(acc[ii][jj] + bc4[jj]);
            *(f16x4*)&Ts[(tx * 4 + jj) * 72 + ty * 4] = hv;
        }
        __syncthreads();
        {
            const int c = t >> 2, seg = t & 3;
            f16x8 r0 = *(const f16x8*)&Ts[c * 72 + seg * 16];
            f16x8 r1 = *(const f16x8*)&Ts[c * 72 + seg * 16 + 8];
            *(f16x8*)&vT[(size_t)(cw0 + c) * NN + m0 + seg * 16]     = r0;
            *(f16x8*)&vT[(size_t)(cw0 + c) * NN + m0 + seg * 16 + 8] = r1;
        }
    }
}

// ---------------------------------------------------------------------------
// K2: scores = k16 @ q16^T via f16 MFMA (dense — every MFMA produces 16x16
// unique outputs). Stores packed (hi, lo) f16x2 per score, single b32 store.
// ---------------------------------------------------------------------------
__global__ __launch_bounds__(256) void k_scores(
    const _Float16* __restrict__ q16, const _Float16* __restrict__ k16,
    f16x2* __restrict__ schl)
{
    const int t    = threadIdx.x;
    const int lane = t & 63;
    const int w    = t >> 6;
    const int col  = lane & 15;
    const int q    = lane >> 4;

    const int i0 = blockIdx.y * 128 + (w >> 1) * 64;
    const int j0 = blockIdx.x * 128 + (w & 1) * 64;

    f32x4 acc[4][4] = {};

    #pragma unroll
    for (int ks = 0; ks < 2; ++ks) {
        f16x8 a[4], b[4];
        #pragma unroll
        for (int f = 0; f < 4; ++f) {
            a[f] = *(const f16x8*)&k16[(size_t)(i0 + f * 16 + col) * 64 + ks * 32 + q * 8];
            b[f] = *(const f16x8*)&q16[(size_t)(j0 + f * 16 + col) * 64 + ks * 32 + q * 8];
        }
        #pragma unroll
        for (int fm = 0; fm < 4; ++fm)
            #pragma unroll
            for (int fn = 0; fn < 4; ++fn)
                acc[fm][fn] = MFMA32(a[fm], b[fn], acc[fm][fn]);
    }

    #pragma unroll
    for (int fm = 0; fm < 4; ++fm)
        #pragma unroll
        for (int fn = 0; fn < 4; ++fn)
            #pragma unroll
            for (int r = 0; r < 4; ++r) {
                const size_t idx = (size_t)(i0 + fm * 16 + q * 4 + r) * NN + j0 + fn * 16 + col;
                const float val = acc[fm][fn][r];
                const _Float16 h = (_Float16)val;
                f16x2 pk; pk[0] = h; pk[1] = (_Float16)(val - (float)h);
                schl[idx] = pk;
            }
}

// ---------------------------------------------------------------------------
// K3: per-edge MLP + row softmax. One block per row, 4 independent waves.
// ZERO LDS-pipe ops in the main loop (no ds_read/write, no shfl/bpermute):
//  - feats arrive via broadcast dword loads: lane (q,col) loads
//    schl[e]/adj[e]/dense[e] at e=st*16+col (16 addrs, L1-served).
//  - B1 built per-lane: q0={shi,slo,a,d}, q1={shi,0,0,0} (A k4=W0lo
//    compensation), q2/3=0.
//  - layer 1 (2x MFMA16) -> relu+pack -> layer 2 (4x MFMA16, chained: C rows
//    q*4+r == B k-slots 4q+j) -> relu+pack -> layer 3 (2x MFMA16, A=W3
//    broadcast) -> C3 holds logit(edge col) in every lane.
// Logits in registers; block softmax; focus overlays schl rows in-place.
// ---------------------------------------------------------------------------
__global__ __launch_bounds__(256) void k_mlp(
    const f16x2* __restrict__ schl,
    const float* __restrict__ adj, const float* __restrict__ dense,
    const float* __restrict__ W1, const float* __restrict__ b1,
    const float* __restrict__ W2, const float* __restrict__ b2,
    const float* __restrict__ W3,
    _Float16* __restrict__ focus)   // row stride 2*NN halves (overlays schl)
{
    __shared__ float red[8];

    const int t    = threadIdx.x;
    const int lane = t & 63;
    const int w    = t >> 6;
    const int col  = lane & 15;
    const int q    = lane >> 4;
    const int i    = blockIdx.x;

    // ---- layer-1 A frags (k=4q+j): q0 slots {W0hi,W0hi,W1_1,W1_2}, q1 k4=W0lo
    f16x4 l1A0 = {}, l1A1 = {};
    {
        const float w0a = W1[col], w0b = W1[col + 16];
        const _Float16 h0a = (_Float16)w0a, h0b = (_Float16)w0b;
        if (q == 0) {
            l1A0[0] = h0a; l1A0[1] = h0a;
            l1A0[2] = (_Float16)W1[32 + col];
            l1A0[3] = (_Float16)W1[64 + col];
            l1A1[0] = h0b; l1A1[1] = h0b;
            l1A1[2] = (_Float16)W1[32 + col + 16];
            l1A1[3] = (_Float16)W1[64 + col + 16];
        } else if (q == 1) {
            l1A0[0] = (_Float16)(w0a - (float)h0a);
            l1A1[0] = (_Float16)(w0b - (float)h0b);
        }
    }

    // ---- layer-2 A frags: w2A[fh][oh][j] = W2[fh*16 + 4q+j][oh*16 + col] ----
    f16x4 w2A[2][2];
    #pragma unroll
    for (int fh = 0; fh < 2; ++fh)
        #pragma unroll
        for (int oh = 0; oh < 2; ++oh)
            #pragma unroll
            for (int j = 0; j < 4; ++j)
                w2A[fh][oh][j] = (_Float16)W2[(fh * 16 + q * 4 + j) * 32 + oh * 16 + col];

    // ---- layer-3 A frags (W3 broadcast over m): a3lo[j]=W3[4q+j] ----
    f16x4 a3lo, a3hi;
    #pragma unroll
    for (int j = 0; j < 4; ++j) {
        a3lo[j] = (_Float16)W3[q * 4 + j];
        a3hi[j] = (_Float16)W3[16 + q * 4 + j];
    }

    // ---- biases (indexed by feat/out = q*4+r) ----
    f32x4 c1a, c1b, c2a, c2b;
    #pragma unroll
    for (int r = 0; r < 4; ++r) {
        c1a[r] = b1[q * 4 + r];
        c1b[r] = b1[16 + q * 4 + r];
        c2a[r] = b2[q * 4 + r];
        c2b[r] = b2[16 + q * 4 + r];
    }

    const f16x2* srow = schl  + (size_t)i * NN;
    const float* arow = adj   + (size_t)i * NN;
    const float* drow = dense + (size_t)i * NN;

    const f32x4 zero4 = {0.f, 0.f, 0.f, 0.f};
    float lg[8];

    for (int c = 0; c < 8; ++c) {
        const int base = w * 512 + c * 64;
        float lgc = 0.f;
        #pragma unroll
        for (int st = 0; st < 4; ++st) {
            const int e = base + st * 16 + col;

            // broadcast loads: 16 unique addrs per col-group, L1-served
            const int d0 = __builtin_bit_cast(int, srow[e]);        // (shi, slo)
            const int d1 = __builtin_bit_cast(int,
                __builtin_amdgcn_cvt_pkrtz(arow[e], drow[e]));      // (a, d)

            const int m0 = (q == 0) ? d0 : ((q == 1) ? (d0 & 0xFFFF) : 0);
            const int m1 = (q == 0) ? d1 : 0;
            i32x2 b1v = {m0, m1};
            f16x4 B1 = __builtin_bit_cast(f16x4, b1v);

            // ---- layer 1 ----
            f32x4 hpA = MFMA16(l1A0, B1, c1a);
            f32x4 hpB = MFMA16(l1A1, B1, c1b);

            // relu + pack: C rows q*4+r -> B2 k-slots 4q+j (no cross-lane)
            i32x2 p0 = { __builtin_bit_cast(int, __builtin_amdgcn_cvt_pkrtz(fmaxf(hpA[0], 0.f), fmaxf(hpA[1], 0.f))),
                         __builtin_bit_cast(int, __builtin_amdgcn_cvt_pkrtz(fmaxf(hpA[2], 0.f), fmaxf(hpA[3], 0.f))) };
            i32x2 p1 = { __builtin_bit_cast(int, __builtin_amdgcn_cvt_pkrtz(fmaxf(hpB[0], 0.f), fmaxf(hpB[1], 0.f))),
                         __builtin_bit_cast(int, __builtin_amdgcn_cvt_pkrtz(fmaxf(hpB[2], 0.f), fmaxf(hpB[3], 0.f))) };
            f16x4 B2f0 = __builtin_bit_cast(f16x4, p0);   // feats 0..15
            f16x4 B2f1 = __builtin_bit_cast(f16x4, p1);   // feats 16..31

            // ---- layer 2 (K-split chained) ----
            f32x4 acc0 = MFMA16(w2A[0][0], B2f0, c2a);
            acc0 = MFMA16(w2A[1][0], B2f1, acc0);
            f32x4 acc1 = MFMA16(w2A[0][1], B2f0, c2b);
            acc1 = MFMA16(w2A[1][1], B2f1, acc1);

            // relu + pack: C2 rows -> B3 k-slots (same chaining)
            i32x2 p3a = { __builtin_bit_cast(int, __builtin_amdgcn_cvt_pkrtz(fmaxf(acc0[0], 0.f), fmaxf(acc0[1], 0.f))),
                          __builtin_bit_cast(int, __builtin_amdgcn_cvt_pkrtz(fmaxf(acc0[2], 0.f), fmaxf(acc0[3], 0.f))) };
            i32x2 p3b = { __builtin_bit_cast(int, __builtin_amdgcn_cvt_pkrtz(fmaxf(acc1[0], 0.f), fmaxf(acc1[1], 0.f))),
                          __builtin_bit_cast(int, __builtin_amdgcn_cvt_pkrtz(fmaxf(acc1[2], 0.f), fmaxf(acc1[3], 0.f))) };
            f16x4 B3f0 = __builtin_bit_cast(f16x4, p3a);  // out-feats 0..15
            f16x4 B3f1 = __builtin_bit_cast(f16x4, p3b);  // out-feats 16..31

            // ---- layer 3: logit in every lane (C3 rows identical) ----
            f32x4 c3 = MFMA16(a3lo, B3f0, zero4);
            c3 = MFMA16(a3hi, B3f1, c3);
            lgc = (q == st) ? c3[0] : lgc;   // lane (q,col) keeps edge q*16+col
        }
        lg[c] = lgc;
    }

    // ---- row softmax (edge = w*512 + c*64 + q*16 + col) ----
    float lmax = -1e30f;
    #pragma unroll
    for (int u = 0; u < 8; ++u) lmax = fmaxf(lmax, lg[u]);
    #pragma unroll
    for (int off = 32; off > 0; off >>= 1)
        lmax = fmaxf(lmax, __shfl_xor(lmax, off, 64));
    if (lane == 0) red[w] = lmax;
    __syncthreads();
    const float rmax = fmaxf(fmaxf(red[0], red[1]), fmaxf(red[2], red[3]));

    float lsum = 0.f;
    #pragma unroll
    for (int u = 0; u < 8; ++u) { lg[u] = __expf(lg[u] - rmax); lsum += lg[u]; }
    #pragma unroll
    for (int off = 32; off > 0; off >>= 1)
        lsum += __shfl_xor(lsum, off, 64);
    if (lane == 0) red[4 + w] = lsum;
    __syncthreads();
    const float inv = 1.f / (red[4] + red[5] + red[6] + red[7]);

    _Float16* hrow = focus + (size_t)i * 2 * NN;
    const int eb = w * 512 + q * 16 + col;
    #pragma unroll
    for (int u = 0; u < 8; ++u)
        hrow[eb + u * 64] = (_Float16)(lg[u] * inv);
}

// ---------------------------------------------------------------------------
// K4: feature = focus @ v via f16 MFMA, K split 4-way across waves + LDS
// reduce. grid (8,128). focus row stride = 2*NN halves (overlaid on schl).
// ---------------------------------------------------------------------------
__global__ __launch_bounds__(256) void k_feat(
    const _Float16* __restrict__ focus, const _Float16* __restrict__ vT,
    float* __restrict__ out)
{
    __shared__ float rbuf[3][64][8];

    const int t    = threadIdx.x;
    const int lane = t & 63;
    const int w    = t >> 6;
    const int col  = lane & 15;
    const int q    = lane >> 4;

    const int m0 = blockIdx.y * 16;
    const int n0 = blockIdx.x * 32;

    f32x4 acc0 = {}, acc1 = {};

    const size_t arow  = (size_t)(m0 + col) * (2 * NN);
    const size_t brow0 = (size_t)(n0 + col) * NN;
    const size_t brow1 = (size_t)(n0 + 16 + col) * NN;
    const int kb = w * 512 + q * 8;

    #pragma unroll 4
    for (int k0 = 0; k0 < 512; k0 += 32) {
        const int ko = kb + k0;
        f16x8 a  = *(const f16x8*)&focus[arow + ko];
        f16x8 b0 = *(const f16x8*)&vT[brow0 + ko];
        f16x8 b1 = *(const f16x8*)&vT[brow1 + ko];
        acc0 = MFMA32(a, b0, acc0);
        acc1 = MFMA32(a, b1, acc1);
    }

    if (w != 0) {
        *(float4*)&rbuf[w - 1][lane][0] = *(float4*)&acc0;
        *(float4*)&rbuf[w - 1][lane][4] = *(float4*)&acc1;
    }
    __syncthreads();

    if (w == 0) {
        #pragma unroll
        for (int j = 0; j < 3; ++j) {
            float4 p0 = *(const float4*)&rbuf[j][lane][0];
            float4 p1 = *(const float4*)&rbuf[j][lane][4];
            acc0[0] += p0.x; acc0[1] += p0.y; acc0[2] += p0.z; acc0[3] += p0.w;
            acc1[0] += p1.x; acc1[1] += p1.y; acc1[2] += p1.z; acc1[3] += p1.w;
        }
        #pragma unroll
        for (int r = 0; r < 4; ++r) {
            out[(size_t)(m0 + q * 4 + r) * DHH + n0 + col]      = acc0[r];
            out[(size_t)(m0 + q * 4 + r) * DHH + n0 + 16 + col] = acc1[r];
        }
    }
}

// ---------------------------------------------------------------------------
extern "C" void kernel_launch(void* const* d_in, const int* in_sizes, int n_in,
                              void* d_out, int out_size, void* d_ws, size_t ws_size,
                              hipStream_t stream) {
    const float* x     = (const float*)d_in[0];
    const float* adj   = (const float*)d_in[1];
    const float* dense = (const float*)d_in[2];
    const float* Wq    = (const float*)d_in[3];
    const float* bq    = (const float*)d_in[4];
    const float* Wk    = (const float*)d_in[5];
    const float* bk    = (const float*)d_in[6];
    const float* Wv    = (const float*)d_in[7];
    const float* bv    = (const float*)d_in[8];
    const float* W1    = (const float*)d_in[9];
    const float* b1    = (const float*)d_in[10];
    const float* W2    = (const float*)d_in[11];
    const float* b2    = (const float*)d_in[12];
    const float* W3    = (const float*)d_in[13];
    float* out = (float*)d_out;

    char* wsb = (char*)d_ws;
    _Float16* q16   = (_Float16*)(wsb);
    _Float16* k16   = (_Float16*)(wsb + 262144);
    _Float16* vT    = (_Float16*)(wsb + 524288);
    f16x2*    schl  = (f16x2*)   (wsb + 1572864);
    _Float16* focus = (_Float16*)(wsb + 1572864);   // row stride 2*NN, in-place

    hipLaunchKernelGGL(k_qkv,    dim3(32, 6),  dim3(256), 0, stream,
                       x, Wq, bq, Wk, bk, Wv, bv, q16, k16, vT);
    hipLaunchKernelGGL(k_scores, dim3(16, 16), dim3(256), 0, stream, q16, k16, schl);
    hipLaunchKernelGGL(k_mlp,    dim3(2048),   dim3(256), 0, stream,
                       schl, adj, dense, W1, b1, W2, b2, W3, focus);
    hipLaunchKernelGGL(k_feat,   dim3(8, 128), dim3(256), 0, stream,
                       focus, vT, out);
}

// Round 12
// 171.653 us; speedup vs baseline: 1.1829x; 1.1040x over previous
//
#include <hip/hip_runtime.h>
#include <math.h>

// N=2048, DH=256, DK=64, FF=32. fp32 in/out, f16 internal.
// ws layout (bytes):
//   q16  @ 0        : 2048x64   f16    (262144)
//   k16  @ 262144   : 2048x64   f16    (262144)
//   vT   @ 524288   : 256x2048  f16    (v transposed)  (1048576)
//   schl @ 1572864  : 2048x2048 f16x2  packed (score_hi, score_lo) (16777216)
//     -> focus (f16) overwrites first half of each schl row in-place;
//        k_feat reads it with row stride 2*NN halves.

#define NN  2048
#define DHH 256
#define DKK 64

typedef float    f32x4 __attribute__((ext_vector_type(4)));
typedef _Float16 f16x8 __attribute__((ext_vector_type(8)));
typedef _Float16 f16x4 __attribute__((ext_vector_type(4)));
typedef _Float16 f16x2 __attribute__((ext_vector_type(2)));
typedef int      i32x2 __attribute__((ext_vector_type(2)));
typedef int      i32x4 __attribute__((ext_vector_type(4)));

// no __has_builtin guard — returns false on the HOST pass (broke R9)
#define MFMA16(a, b, c) __builtin_amdgcn_mfma_f32_16x16x16f16((a), (b), (c), 0, 0, 0)
#define MFMA32(a, b, c) __builtin_amdgcn_mfma_f32_16x16x32_f16((a), (b), (c), 0, 0, 0)

// pack two f32 (RTZ) then relu on the packed pair (v_cvt_pkrtz + v_pk_max_f16).
// Bit-identical to relu-then-pack: pkrtz(neg) is neg, max(.,0) -> +0.
__device__ __forceinline__ int rp2(float x, float y) {
    f16x2 v = __builtin_bit_cast(f16x2, __builtin_amdgcn_cvt_pkrtz(x, y));
    const f16x2 z = {(_Float16)0, (_Float16)0};
    v = __builtin_elementwise_max(v, z);
    return __builtin_bit_cast(int, v);
}

// ---------------------------------------------------------------------------
// K1: qkv projections (fp32 math). q,k stored f16 row-major; v stored f16
// transposed. grid (32, 6).
// ---------------------------------------------------------------------------
__global__ __launch_bounds__(256) void k_qkv(
    const float* __restrict__ x,
    const float* __restrict__ Wq, const float* __restrict__ bq,
    const float* __restrict__ Wk, const float* __restrict__ bk,
    const float* __restrict__ Wv, const float* __restrict__ bv,
    _Float16* __restrict__ q16, _Float16* __restrict__ k16,
    _Float16* __restrict__ vT)
{
    __shared__ float As[32][64];
    __shared__ float Bs[32][64];
    __shared__ _Float16 Ts[64 * 72];

    const int t  = threadIdx.x;
    const int m0 = blockIdx.x * 64;
    const int yb = blockIdx.y;

    const float* W; const float* bias; int wld; int cw0;
    if (yb == 0)      { W = Wq; bias = bq; wld = 64;  cw0 = 0; }
    else if (yb == 1) { W = Wk; bias = bk; wld = 64;  cw0 = 0; }
    else              { W = Wv; bias = bv; wld = 256; cw0 = (yb - 2) * 64; }

    const int tx = t & 15, ty = t >> 4;
    float acc[4][4] = {};

    for (int k0 = 0; k0 < DHH; k0 += 32) {
        {
            const int rr = t >> 3;
            const int cc = (t & 7) * 4;
            float4 a0 = *(const float4*)(x + (size_t)(m0 + rr)      * DHH + k0 + cc);
            float4 a1 = *(const float4*)(x + (size_t)(m0 + rr + 32) * DHH + k0 + cc);
            As[cc+0][rr]    = a0.x; As[cc+1][rr]    = a0.y; As[cc+2][rr]    = a0.z; As[cc+3][rr]    = a0.w;
            As[cc+0][rr+32] = a1.x; As[cc+1][rr+32] = a1.y; As[cc+2][rr+32] = a1.z; As[cc+3][rr+32] = a1.w;
        }
        {
            const int bk_ = t >> 4;
            const int bc  = (t & 15) * 4;
            *(float4*)&Bs[bk_][bc]      = *(const float4*)(W + (size_t)(k0 + bk_)      * wld + cw0 + bc);
            *(float4*)&Bs[bk_ + 16][bc] = *(const float4*)(W + (size_t)(k0 + bk_ + 16) * wld + cw0 + bc);
        }
        __syncthreads();
        #pragma unroll
        for (int kk = 0; kk < 32; ++kk) {
            float4 a = *(const float4*)&As[kk][ty * 4];
            float4 b = *(const float4*)&Bs[kk][tx * 4];
            float av[4] = {a.x, a.y, a.z, a.w};
            float bw[4] = {b.x, b.y, b.z, b.w};
            #pragma unroll
            for (int ii = 0; ii < 4; ++ii)
                #pragma unroll
                for (int jj = 0; jj < 4; ++jj)
                    acc[ii][jj] = fmaf(av[ii], bw[jj], acc[ii][jj]);
        }
        __syncthreads();
    }

    float4 b4 = *(const float4*)&bias[cw0 + tx * 4];
    float bc4[4] = {b4.x, b4.y, b4.z, b4.w};

    if (yb < 2) {
        _Float16* outp = (yb == 0) ? q16 : k16;
        #pragma unroll
        for (int ii = 0; ii < 4; ++ii) {
            f16x4 hv;
            #pragma unroll
            for (int jj = 0; jj < 4; ++jj) hv[jj] = (_Float16)(acc[ii][jj] + bc4[jj]);
            *(f16x4*)&outp[(size_t)(m0 + ty * 4 + ii) * 64 + tx * 4] = hv;
        }
    } else {
        #pragma unroll
        for (int jj = 0; jj < 4; ++jj) {
            f16x4 hv;
            #pragma unroll
            for (int ii = 0; ii < 4; ++ii) hv[ii] = (_Float16)(acc[ii][jj] + bc4[jj]);
            *(f16x4*)&Ts[(tx * 4 + jj) * 72 + ty * 4] = hv;
        }
        __syncthreads();
        {
            const int c = t >> 2, seg = t & 3;
            f16x8 r0 = *(const f16x8*)&Ts[c * 72 + seg * 16];
            f16x8 r1 = *(const f16x8*)&Ts[c * 72 + seg * 16 + 8];
            *(f16x8*)&vT[(size_t)(cw0 + c) * NN + m0 + seg * 16]     = r0;
            *(f16x8*)&vT[(size_t)(cw0 + c) * NN + m0 + seg * 16 + 8] = r1;
        }
    }
}

// ---------------------------------------------------------------------------
// K2: scores = k16 @ q16^T via f16 MFMA (dense). Packed (hi, lo) f16x2 out.
// ---------------------------------------------------------------------------
__global__ __launch_bounds__(256) void k_scores(
    const _Float16* __restrict__ q16, const _Float16* __restrict__ k16,
    f16x2* __restrict__ schl)
{
    const int t    = threadIdx.x;
    const int lane = t & 63;
    const int w    = t >> 6;
    const int col  = lane & 15;
    const int q    = lane >> 4;

    const int i0 = blockIdx.y * 128 + (w >> 1) * 64;
    const int j0 = blockIdx.x * 128 + (w & 1) * 64;

    f32x4 acc[4][4] = {};

    #pragma unroll
    for (int ks = 0; ks < 2; ++ks) {
        f16x8 a[4], b[4];
        #pragma unroll
        for (int f = 0; f < 4; ++f) {
            a[f] = *(const f16x8*)&k16[(size_t)(i0 + f * 16 + col) * 64 + ks * 32 + q * 8];
            b[f] = *(const f16x8*)&q16[(size_t)(j0 + f * 16 + col) * 64 + ks * 32 + q * 8];
        }
        #pragma unroll
        for (int fm = 0; fm < 4; ++fm)
            #pragma unroll
            for (int fn = 0; fn < 4; ++fn)
                acc[fm][fn] = MFMA32(a[fm], b[fn], acc[fm][fn]);
    }

    #pragma unroll
    for (int fm = 0; fm < 4; ++fm)
        #pragma unroll
        for (int fn = 0; fn < 4; ++fn)
            #pragma unroll
            for (int r = 0; r < 4; ++r) {
                const size_t idx = (size_t)(i0 + fm * 16 + q * 4 + r) * NN + j0 + fn * 16 + col;
                const float val = acc[fm][fn][r];
                const _Float16 h = (_Float16)val;
                f16x2 pk; pk[0] = h; pk[1] = (_Float16)(val - (float)h);
                schl[idx] = pk;
            }
}

// ---------------------------------------------------------------------------
// K3: per-edge MLP + row softmax. Zero LDS-pipe ops in the main loop.
// Changes vs R11 (both VALU-stream diet, numerics identical):
//  - edge remap e = base + 4*col + st: ONE dwordx4 load per operand per
//    64-edge chunk (3 loads vs 12) with free per-st element extraction.
//  - relu via v_pk_max_f16 after packing (rp2): 6 VALU per layer-pack vs 12.
// ---------------------------------------------------------------------------
__global__ __launch_bounds__(256) void k_mlp(
    const f16x2* __restrict__ schl,
    const float* __restrict__ adj, const float* __restrict__ dense,
    const float* __restrict__ W1, const float* __restrict__ b1,
    const float* __restrict__ W2, const float* __restrict__ b2,
    const float* __restrict__ W3,
    _Float16* __restrict__ focus)   // row stride 2*NN halves (overlays schl)
{
    __shared__ float red[8];

    const int t    = threadIdx.x;
    const int lane = t & 63;
    const int w    = t >> 6;
    const int col  = lane & 15;
    const int q    = lane >> 4;
    const int i    = blockIdx.x;

    // ---- layer-1 A frags (k=4q+j): q0 {W0hi,W0hi,W1_1,W1_2}, q1 k4=W0lo ----
    f16x4 l1A0 = {}, l1A1 = {};
    {
        const float w0a = W1[col], w0b = W1[col + 16];
        const _Float16 h0a = (_Float16)w0a, h0b = (_Float16)w0b;
        if (q == 0) {
            l1A0[0] = h0a; l1A0[1] = h0a;
            l1A0[2] = (_Float16)W1[32 + col];
            l1A0[3] = (_Float16)W1[64 + col];
            l1A1[0] = h0b; l1A1[1] = h0b;
            l1A1[2] = (_Float16)W1[32 + col + 16];
            l1A1[3] = (_Float16)W1[64 + col + 16];
        } else if (q == 1) {
            l1A0[0] = (_Float16)(w0a - (float)h0a);
            l1A1[0] = (_Float16)(w0b - (float)h0b);
        }
    }

    // ---- layer-2 A frags: w2A[fh][oh][j] = W2[fh*16 + 4q+j][oh*16 + col] ----
    f16x4 w2A[2][2];
    #pragma unroll
    for (int fh = 0; fh < 2; ++fh)
        #pragma unroll
        for (int oh = 0; oh < 2; ++oh)
            #pragma unroll
            for (int j = 0; j < 4; ++j)
                w2A[fh][oh][j] = (_Float16)W2[(fh * 16 + q * 4 + j) * 32 + oh * 16 + col];

    // ---- layer-3 A frags (W3 broadcast over m) ----
    f16x4 a3lo, a3hi;
    #pragma unroll
    for (int j = 0; j < 4; ++j) {
        a3lo[j] = (_Float16)W3[q * 4 + j];
        a3hi[j] = (_Float16)W3[16 + q * 4 + j];
    }

    // ---- biases (indexed by feat/out = q*4+r) ----
    f32x4 c1a, c1b, c2a, c2b;
    #pragma unroll
    for (int r = 0; r < 4; ++r) {
        c1a[r] = b1[q * 4 + r];
        c1b[r] = b1[16 + q * 4 + r];
        c2a[r] = b2[q * 4 + r];
        c2b[r] = b2[16 + q * 4 + r];
    }

    const f16x2* srow = schl  + (size_t)i * NN;
    const float* arow = adj   + (size_t)i * NN;
    const float* drow = dense + (size_t)i * NN;

    const f32x4 zero4 = {0.f, 0.f, 0.f, 0.f};
    float lg[8];

    for (int c = 0; c < 8; ++c) {
        const int base = w * 512 + c * 64;
        const int eb4  = base + col * 4;     // this lane's 4 edges (st=0..3)

        // one 16B load per operand per chunk (16 unique addrs, L1 broadcast)
        i32x4  sv = *(const i32x4*)&srow[eb4];      // 4x (shi, slo)
        float4 av = *(const float4*)&arow[eb4];
        float4 dv = *(const float4*)&drow[eb4];
        const float aa[4] = {av.x, av.y, av.z, av.w};
        const float dd[4] = {dv.x, dv.y, dv.z, dv.w};

        float lgc = 0.f;
        #pragma unroll
        for (int st = 0; st < 4; ++st) {
            const int d0 = sv[st];
            const int d1 = __builtin_bit_cast(int,
                __builtin_amdgcn_cvt_pkrtz(aa[st], dd[st]));

            const int m0 = (q == 0) ? d0 : ((q == 1) ? (d0 & 0xFFFF) : 0);
            const int m1 = (q == 0) ? d1 : 0;
            i32x2 b1v = {m0, m1};
            f16x4 B1 = __builtin_bit_cast(f16x4, b1v);

            // ---- layer 1 ----
            f32x4 hpA = MFMA16(l1A0, B1, c1a);
            f32x4 hpB = MFMA16(l1A1, B1, c1b);

            i32x2 p0 = { rp2(hpA[0], hpA[1]), rp2(hpA[2], hpA[3]) };
            i32x2 p1 = { rp2(hpB[0], hpB[1]), rp2(hpB[2], hpB[3]) };
            f16x4 B2f0 = __builtin_bit_cast(f16x4, p0);   // feats 0..15
            f16x4 B2f1 = __builtin_bit_cast(f16x4, p1);   // feats 16..31

            // ---- layer 2 (K-split chained) ----
            f32x4 acc0 = MFMA16(w2A[0][0], B2f0, c2a);
            acc0 = MFMA16(w2A[1][0], B2f1, acc0);
            f32x4 acc1 = MFMA16(w2A[0][1], B2f0, c2b);
            acc1 = MFMA16(w2A[1][1], B2f1, acc1);

            i32x2 p3a = { rp2(acc0[0], acc0[1]), rp2(acc0[2], acc0[3]) };
            i32x2 p3b = { rp2(acc1[0], acc1[1]), rp2(acc1[2], acc1[3]) };
            f16x4 B3f0 = __builtin_bit_cast(f16x4, p3a);
            f16x4 B3f1 = __builtin_bit_cast(f16x4, p3b);

            // ---- layer 3: logit in every lane (C3 rows identical) ----
            f32x4 c3 = MFMA16(a3lo, B3f0, zero4);
            c3 = MFMA16(a3hi, B3f1, c3);
            lgc = (q == st) ? c3[0] : lgc;   // lane (q,col): edge base+4*col+q
        }
        lg[c] = lgc;
    }

    // ---- row softmax (edge = w*512 + c*64 + 4*col + q) ----
    float lmax = -1e30f;
    #pragma unroll
    for (int u = 0; u < 8; ++u) lmax = fmaxf(lmax, lg[u]);
    #pragma unroll
    for (int off = 32; off > 0; off >>= 1)
        lmax = fmaxf(lmax, __shfl_xor(lmax, off, 64));
    if (lane == 0) red[w] = lmax;
    __syncthreads();
    const float rmax = fmaxf(fmaxf(red[0], red[1]), fmaxf(red[2], red[3]));

    float lsum = 0.f;
    #pragma unroll
    for (int u = 0; u < 8; ++u) { lg[u] = __expf(lg[u] - rmax); lsum += lg[u]; }
    #pragma unroll
    for (int off = 32; off > 0; off >>= 1)
        lsum += __shfl_xor(lsum, off, 64);
    if (lane == 0) red[4 + w] = lsum;
    __syncthreads();
    const float inv = 1.f / (red[4] + red[5] + red[6] + red[7]);

    _Float16* hrow = focus + (size_t)i * 2 * NN;
    const int eb = w * 512 + 4 * col + q;
    #pragma unroll
    for (int u = 0; u < 8; ++u)
        hrow[eb + u * 64] = (_Float16)(lg[u] * inv);
}

// ---------------------------------------------------------------------------
// K4: feature = focus @ v via f16 MFMA, K split 4-way across waves + LDS
// reduce. grid (8,128). focus row stride = 2*NN halves (overlaid on schl).
// ---------------------------------------------------------------------------
__global__ __launch_bounds__(256) void k_feat(
    const _Float16* __restrict__ focus, const _Float16* __restrict__ vT,
    float* __restrict__ out)
{
    __shared__ float rbuf[3][64][8];

    const int t    = threadIdx.x;
    const int lane = t & 63;
    const int w    = t >> 6;
    const int col  = lane & 15;
    const int q    = lane >> 4;

    const int m0 = blockIdx.y * 16;
    const int n0 = blockIdx.x * 32;

    f32x4 acc0 = {}, acc1 = {};

    const size_t arow  = (size_t)(m0 + col) * (2 * NN);
    const size_t brow0 = (size_t)(n0 + col) * NN;
    const size_t brow1 = (size_t)(n0 + 16 + col) * NN;
    const int kb = w * 512 + q * 8;

    #pragma unroll 4
    for (int k0 = 0; k0 < 512; k0 += 32) {
        const int ko = kb + k0;
        f16x8 a  = *(const f16x8*)&focus[arow + ko];
        f16x8 b0 = *(const f16x8*)&vT[brow0 + ko];
        f16x8 b1 = *(const f16x8*)&vT[brow1 + ko];
        acc0 = MFMA32(a, b0, acc0);
        acc1 = MFMA32(a, b1, acc1);
    }

    if (w != 0) {
        *(float4*)&rbuf[w - 1][lane][0] = *(float4*)&acc0;
        *(float4*)&rbuf[w - 1][lane][4] = *(float4*)&acc1;
    }
    __syncthreads();

    if (w == 0) {
        #pragma unroll
        for (int j = 0; j < 3; ++j) {
            float4 p0 = *(const float4*)&rbuf[j][lane][0];
            float4 p1 = *(const float4*)&rbuf[j][lane][4];
            acc0[0] += p0.x; acc0[1] += p0.y; acc0[2] += p0.z; acc0[3] += p0.w;
            acc1[0] += p1.x; acc1[1] += p1.y; acc1[2] += p1.z; acc1[3] += p1.w;
        }
        #pragma unroll
        for (int r = 0; r < 4; ++r) {
            out[(size_t)(m0 + q * 4 + r) * DHH + n0 + col]      = acc0[r];
            out[(size_t)(m0 + q * 4 + r) * DHH + n0 + 16 + col] = acc1[r];
        }
    }
}

// ---------------------------------------------------------------------------
extern "C" void kernel_launch(void* const* d_in, const int* in_sizes, int n_in,
                              void* d_out, int out_size, void* d_ws, size_t ws_size,
                              hipStream_t stream) {
    const float* x     = (const float*)d_in[0];
    const float* adj   = (const float*)d_in[1];
    const float* dense = (const float*)d_in[2];
    const float* Wq    = (const float*)d_in[3];
    const float* bq    = (const float*)d_in[4];
    const float* Wk    = (const float*)d_in[5];
    const float* bk    = (const float*)d_in[6];
    const float* Wv    = (const float*)d_in[7];
    const float* bv    = (const float*)d_in[8];
    const float* W1    = (const float*)d_in[9];
    const float* b1    = (const float*)d_in[10];
    const float* W2    = (const float*)d_in[11];
    const float* b2    = (const float*)d_in[12];
    const float* W3    = (const float*)d_in[13];
    float* out = (float*)d_out;

    char* wsb = (char*)d_ws;
    _Float16* q16   = (_Float16*)(wsb);
    _Float16* k16   = (_Float16*)(wsb + 262144);
    _Float16* vT    = (_Float16*)(wsb + 524288);
    f16x2*    schl  = (f16x2*)   (wsb + 1572864);
    _Float16* focus = (_Float16*)(wsb + 1572864);   // row stride 2*NN, in-place

    hipLaunchKernelGGL(k_qkv,    dim3(32, 6),  dim3(256), 0, stream,
                       x, Wq, bq, Wk, bk, Wv, bv, q16, k16, vT);
    hipLaunchKernelGGL(k_scores, dim3(16, 16), dim3(256), 0, stream, q16, k16, schl);
    hipLaunchKernelGGL(k_mlp,    dim3(2048),   dim3(256), 0, stream,
                       schl, adj, dense, W1, b1, W2, b2, W3, focus);
    hipLaunchKernelGGL(k_feat,   dim3(8, 128), dim3(256), 0, stream,
                       focus, vT, out);
}